// Round 12
// baseline (728.220 us; speedup 1.0000x reference)
//
#include <hip/hip_runtime.h>
#include <hip/hip_bf16.h>

// B=1, H=16, S=2048, KV=4096, D=64
// out[q][d] = (KEEP/sum_k p_k) * sum_k (drop_k * p_k * V[k][d])
// STATIC-MAX softmax: p = exp(s-8), s = qk/8 + {0,1} additive mask.
// attn: 128q/block, 32x32 MFMA, in-reg P, fused ballot mask streaming.
// R12: NSPLIT=4 (4 blocks/CU, 4 waves/SIMD), per-kv-half pipeline to fit
// 128 VGPR under __launch_bounds__(256,4).

#define H_   16
#define S_   2048
#define KV_  4096
#define D_   64
#define NSPLIT 4
#define CPB  16                // chunks per block task = KV/64/NSPLIT

using bf16x8 = __attribute__((ext_vector_type(8))) __bf16;
using f32x4  = __attribute__((ext_vector_type(4))) float;
using f32x16 = __attribute__((ext_vector_type(16))) float;
using uintx4 = __attribute__((ext_vector_type(4))) unsigned;

constexpr float KEEP_SCALE = (float)(1.0 / (1.0 - 0.31881923790897965));
#define C_SC  0.18033688011112043f     // 0.125*log2(e)
#define C_ONE -10.098865286222744f     // (1-8)*log2(e)
#define C_ZRO -11.541560327111707f     // (0-8)*log2(e)

// ---- workspace layout (~49MB of ~2GB) ----
#define WS_FLAG 0
#define WS_K    256                        //  8 MB frag-ordered K tiles
#define WS_V    (WS_K + 8388608)           //  8 MB frag-ordered V^T tiles
#define WS_PART (WS_V + 8388608)           // 32 MB [4][H*S][64] f32
#define WS_LS   (WS_PART + 33554432)       // 512 KB [4][H*S] f32

__device__ __forceinline__ bf16x8 as_bf16x8(uintx4 v) {
    bf16x8 r; __builtin_memcpy(&r, &v, 16); return r;
}
__device__ __forceinline__ void gld16(const void* g, void* l) {
    __builtin_amdgcn_global_load_lds(
        (const __attribute__((address_space(1))) unsigned*)g,
        (__attribute__((address_space(3))) unsigned*)l, 16, 0, 0);
}

// ---------------------------------------------------------------------------
__global__ void detect_mask(const unsigned* __restrict__ m, int* __restrict__ flag) {
    __shared__ int bad;
    if (threadIdx.x == 0) bad = 0;
    __syncthreads();
    int ok = 1;
    for (int i = threadIdx.x; i < 4096; i += blockDim.x) {
        unsigned w = m[i];
        if (w > 1u && w != 0x3F800000u) ok = 0;
    }
    if (!ok) atomicOr(&bad, 1);
    __syncthreads();
    if (threadIdx.x == 0) *flag = bad;
}

// ---------------------------------------------------------------------------
// Fragment-order K/V^T tiles, one block per (h, chunk). 16B unit u, lane
// l = u&63, g8 = u>>6:
//  K: K[c*64 + (g8>>2)*32 + (l&31)][(g8&3)*16 + (l>>5)*8 + 0..7]
//  V: V^T[(g8>>2)*32 + (l&31)][(g8&3)*16 + (l>>5)*8 + 0..7]
// ---------------------------------------------------------------------------
__global__ __launch_bounds__(256)
void conv_kv(const float* __restrict__ K, const float* __restrict__ V,
             char* __restrict__ kt, char* __restrict__ vt) {
    __shared__ __bf16 Ks[64][72];
    __shared__ __bf16 Vs[64][72];        // transposed: [d][kv]
    const int hc = blockIdx.x;           // h*64 + c
    const int h = hc >> 6, c = hc & 63;
    const int tid = threadIdx.x;
    const float* ksrc = K + ((size_t)h * KV_ + c * 64) * D_;
    const float* vsrc = V + ((size_t)h * KV_ + c * 64) * D_;
    #pragma unroll
    for (int it = 0; it < 4; ++it) {
        const int f = it * 1024 + tid * 4;
        const int row = f >> 6, col = f & 63;
        f32x4 a = *(const f32x4*)(ksrc + f);
        f32x4 v = *(const f32x4*)(vsrc + f);
        #pragma unroll
        for (int e = 0; e < 4; ++e) {
            Ks[row][col + e] = (__bf16)a[e];
            Vs[col + e][row] = (__bf16)v[e];
        }
    }
    __syncthreads();
    char* kdst = kt + (size_t)hc * 8192;
    char* vdst = vt + (size_t)hc * 8192;
    #pragma unroll
    for (int r = 0; r < 2; ++r) {
        const int u = r * 256 + tid;
        const int g8 = u >> 6, l = u & 63;
        const int lo = l & 31, hi = l >> 5;
        const int aa = g8 >> 2, bb = g8 & 3;
        *(bf16x8*)(kdst + u * 16) = *(const bf16x8*)&Ks[aa * 32 + lo][bb * 16 + hi * 8];
        *(bf16x8*)(vdst + u * 16) = *(const bf16x8*)&Vs[aa * 32 + lo][bb * 16 + hi * 8];
    }
}

// ---------------------------------------------------------------------------
// attn: 4 waves x 32q = 128 q/block; chunk = 64 kv; NSPLIT=4 -> 1024 blocks
// (4/CU, 4 waves/SIMD). Per-kv-half pipeline keeps VGPR <= 128.
// ---------------------------------------------------------------------------
__global__ __launch_bounds__(256, 4)
void attn_fwd(const float* __restrict__ Q,
              const unsigned char* __restrict__ Mb,
              const int* __restrict__ flagp,
              const char* __restrict__ Ktiles,
              const char* __restrict__ Vtiles,
              float* __restrict__ Part,
              float* __restrict__ Ls)
{
    __shared__ char smem[32768];          // 2 x (K 8KB | V 8KB)

    const int tid  = threadIdx.x;
    const int wave = tid >> 6, lane = tid & 63;
    const int lo   = lane & 31, hi = lane >> 5;

    // XCD swizzle (1024 % 8 == 0): 128 consecutive wg per XCD = 2 heads
    const int b  = blockIdx.x;
    const int wg = (b & 7) * 128 + (b >> 3);
    const int h  = wg >> 6;
    const int rr = wg & 63, split = rr >> 4, qt = rr & 15;
    const int q0w = qt * 128 + wave * 32;
    const int q_g = q0w + lo;

    const bool byteMode = (*flagp != 0);
    const unsigned* Mw = (const unsigned*)Mb;

    // Q fragments (B operand): lane holds Q[q_g][dt*16 + hi*8 + 0..7]
    bf16x8 bq[4];
    {
        const float* qrow = Q + ((size_t)h * S_ + q_g) * D_;
        #pragma unroll
        for (int dt = 0; dt < 4; ++dt) {
            f32x4 f0 = *(const f32x4*)(qrow + dt * 16 + hi * 8);
            f32x4 f1 = *(const f32x4*)(qrow + dt * 16 + hi * 8 + 4);
            bf16x8 bb;
            #pragma unroll
            for (int e = 0; e < 4; ++e) { bb[e] = (__bf16)f0[e]; bb[4 + e] = (__bf16)f1[e]; }
            bq[dt] = bb;
        }
    }

    const char* gK = Ktiles + (size_t)h * 64 * 8192;
    const char* gV = Vtiles + (size_t)h * 64 * 8192;
    float lsum = 0.f;
    f32x16 acc0 = {}, acc1 = {};          // d = lo / 32+lo ; q = (r&3)+8*(r>>2)+4*hi

    auto stage = [&](int buf, int c) {
        const char* sk = gK + (size_t)c * 8192 + tid * 16;
        const char* sv = gV + (size_t)c * 8192 + tid * 16;
        char* dk = smem + buf * 16384 + tid * 16;
        gld16(sk,        dk);
        gld16(sk + 4096, dk + 4096);
        gld16(sv,        dk + 8192);
        gld16(sv + 4096, dk + 12288);
    };

    // --- fused mask streaming: wave packs q rows [q0w, q0w+32) of chunk cc.
    unsigned mreg[32];
    auto load_bits = [&](int cc) {
        if (byteMode) {
            const unsigned char* base = Mb + ((size_t)h * S_ + q0w) * KV_ + (size_t)cc * 64 + lane;
            #pragma unroll
            for (int i = 0; i < 32; ++i) mreg[i] = base[(size_t)i * KV_];
        } else {
            const unsigned* base = Mw + ((size_t)h * S_ + q0w) * KV_ + (size_t)cc * 64 + lane;
            #pragma unroll
            for (int i = 0; i < 32; ++i) mreg[i] = base[(size_t)i * KV_];
        }
    };
    auto ballot_bits = [&]() -> unsigned long long {
        unsigned long long sav = 0;
        #pragma unroll
        for (int i = 0; i < 32; ++i) {
            unsigned long long bal = __ballot(mreg[i] != 0u);
            if ((lane & 31) == i) sav = bal;   // both half-lanes keep word i=lo
        }
        return sav;
    };

    const int cs = split * CPB, ce = cs + CPB;
    load_bits(cs);
    stage(0, cs);
    unsigned long long mb_cur = ballot_bits();
    __syncthreads();
    int cur = 0;

    for (int c = cs; c < ce; ++c) {
        const bool more = (c + 1 < ce);
        if (more) load_bits(c + 1);           // HBM stream, consumed next iter
        if (more) stage(cur ^ 1, c + 1);
        const unsigned long long mb = mb_cur;
        const char* Kb = smem + cur * 16384;
        const char* Vb = Kb + 8192;

        // ---- per-kv-half pipeline: QK^T(kvt) -> exp/pack -> PV(kvt)
        #pragma unroll
        for (int kvt = 0; kvt < 2; ++kvt) {
            f32x16 st = {};
            __builtin_amdgcn_s_setprio(1);
            #pragma unroll
            for (int dt = 0; dt < 4; ++dt) {
                bf16x8 kfr = *(const bf16x8*)(Kb + ((kvt * 4 + dt) * 64 + lane) * 16);
                st = __builtin_amdgcn_mfma_f32_32x32x16_bf16(kfr, bq[dt], st, 0, 0, 0);
            }
            __builtin_amdgcn_s_setprio(0);

            float pd[16];
            #pragma unroll
            for (int r = 0; r < 16; ++r) {
                const int kvl = kvt * 32 + (r & 3) + 8 * (r >> 2) + 4 * hi;
                const int kvg = c * 64 + kvl;
                const bool one = (kvg < S_) ? (kvg > q_g) : (kvg - S_ <= q_g);
                float v = fmaf(st[r], C_SC, one ? C_ONE : C_ZRO);
                float pp = exp2f(v);
                lsum += pp;
                pd[r] = ((mb >> kvl) & 1) ? pp : 0.f;
            }
            unsigned pk[8], X[8];
            #pragma unroll
            for (int j = 0; j < 8; ++j) {
                unsigned t;
                asm("v_cvt_pk_bf16_f32 %0, %1, %2" : "=v"(t) : "v"(pd[2 * j]), "v"(pd[2 * j + 1]));
                pk[j] = t;
            }
            #pragma unroll
            for (int j = 0; j < 8; ++j) X[j] = (unsigned)__shfl_xor((int)pk[j], 32);
            uintx4 f0, f1;
            if (hi) {
                f0 = (uintx4){X[2], X[3], pk[2], pk[3]};
                f1 = (uintx4){X[6], X[7], pk[6], pk[7]};
            } else {
                f0 = (uintx4){pk[0], pk[1], X[0], X[1]};
                f1 = (uintx4){pk[4], pk[5], X[4], X[5]};
            }
            bf16x8 pf0 = as_bf16x8(f0);       // kv kvt*32 + 0..15
            bf16x8 pf1 = as_bf16x8(f1);       // kv kvt*32 + 16..31

            __builtin_amdgcn_s_setprio(1);
            #pragma unroll
            for (int j = 0; j < 2; ++j) {
                const int kvk = kvt * 2 + j;
                bf16x8 pfj = j ? pf1 : pf0;
                bf16x8 v0 = *(const bf16x8*)(Vb + ((kvk)     * 64 + lane) * 16);
                bf16x8 v1 = *(const bf16x8*)(Vb + ((4 + kvk) * 64 + lane) * 16);
                acc0 = __builtin_amdgcn_mfma_f32_32x32x16_bf16(pfj, v0, acc0, 0, 0, 0);
                acc1 = __builtin_amdgcn_mfma_f32_32x32x16_bf16(pfj, v1, acc1, 0, 0, 0);
            }
            __builtin_amdgcn_s_setprio(0);
        }

        // ---- ballot chunk c+1 (mask loads have drained by now)
        if (more) mb_cur = ballot_bits();

        __syncthreads();     // readers done + next stage (vmcnt) drained
        cur ^= 1;
    }

    // ---- epilogue
    lsum += __shfl_xor(lsum, 32);
    if (hi == 0) Ls[((size_t)split * H_ + h) * S_ + q_g] = lsum;
    float* pa = Part + ((size_t)split * H_ + h) * S_ * 64;
    #pragma unroll
    for (int r = 0; r < 16; ++r) {
        const int q = q0w + (r & 3) + 8 * (r >> 2) + 4 * hi;
        __builtin_nontemporal_store(acc0[r], pa + (size_t)q * 64 + lo);
        __builtin_nontemporal_store(acc1[r], pa + (size_t)q * 64 + 32 + lo);
    }
}

// out = KEEP * sum_sp part / sum_sp ls
__global__ __launch_bounds__(256)
void combine(const float* __restrict__ Part, const float* __restrict__ Ls,
             float* __restrict__ Out) {
    const int idx = blockIdx.x * 256 + threadIdx.x;   // H*S*16
    const int r  = idx >> 4;
    const int dg = (idx & 15) * 4;
    f32x4 s = {0.f, 0.f, 0.f, 0.f};
    float l = 0.f;
    #pragma unroll
    for (int sp = 0; sp < NSPLIT; ++sp) {
        const f32x4 a = *(const f32x4*)(Part + ((size_t)sp * H_ * S_ + r) * D_ + dg);
        #pragma unroll
        for (int e = 0; e < 4; ++e) s[e] += a[e];
        l += Ls[(size_t)sp * H_ * S_ + r];
    }
    const float k = KEEP_SCALE / l;
    f32x4 o;
    #pragma unroll
    for (int e = 0; e < 4; ++e) o[e] = s[e] * k;
    *(f32x4*)(Out + (size_t)r * D_ + dg) = o;
}

extern "C" void kernel_launch(void* const* d_in, const int* in_sizes, int n_in,
                              void* d_out, int out_size, void* d_ws, size_t ws_size,
                              hipStream_t stream) {
    const float* Q = (const float*)d_in[0];
    const float* K = (const float*)d_in[1];
    const float* V = (const float*)d_in[2];
    const unsigned char* M = (const unsigned char*)d_in[3];
    char* ws = (char*)d_ws;
    int* flag = (int*)(ws + WS_FLAG);
    char* kt = ws + WS_K;
    char* vt = ws + WS_V;
    float* part = (float*)(ws + WS_PART);
    float* ls = (float*)(ws + WS_LS);

    detect_mask<<<1, 256, 0, stream>>>((const unsigned*)M, flag);
    conv_kv<<<1024, 256, 0, stream>>>(K, V, kt, vt);
    attn_fwd<<<1024, 256, 0, stream>>>(Q, M, flag, kt, vt, part, ls);
    combine<<<2048, 256, 0, stream>>>(part, ls, (float*)d_out);
}

// Round 13
// 175.345 us; speedup vs baseline: 4.1531x; 4.1531x over previous
//
#include <hip/hip_runtime.h>
#include <hip/hip_bf16.h>

// B=1, H=16, S=2048, KV=4096, D=64
// out[q][d] = (KEEP/sum_k p_k) * sum_k (drop_k * p_k * V[k][d])
// STATIC-MAX softmax: p = exp(s-8), s = qk/8 + {0,1} additive mask.
// R13: 8 waves x 16q (16x16x32 MFMA, r4-verified layouts), 512-thr blocks,
// __launch_bounds__(512,4) -> 4 waves/SIMD with ~85 VGPR (no spill),
// fused ballot mask streaming (r11), swizzled LDS K/V + P tiles.

#define H_   16
#define S_   2048
#define KV_  4096
#define D_   64
#define NSPLIT 2
#define CPB  32                // chunks per block task

using bf16x8 = __attribute__((ext_vector_type(8))) __bf16;
using bf16x4 = __attribute__((ext_vector_type(4))) __bf16;
using f32x4  = __attribute__((ext_vector_type(4))) float;
using uintx4 = __attribute__((ext_vector_type(4))) unsigned;

constexpr float KEEP_SCALE = (float)(1.0 / (1.0 - 0.31881923790897965));
#define C_SC  0.18033688011112043f     // 0.125*log2(e)
#define C_ONE -10.098865286222744f     // (1-8)*log2(e)
#define C_ZRO -11.541560327111707f     // (0-8)*log2(e)

// ---- workspace layout (~33MB of ~2GB) ----
#define WS_FLAG 0
#define WS_K    256                        //  8 MB swizzled K tiles
#define WS_V    (WS_K + 8388608)           //  8 MB swizzled V^T tiles
#define WS_PART (WS_V + 8388608)           // 16 MB [2][H*S][64] f32
#define WS_LS   (WS_PART + 16777216)       // 256 KB [2][H*S] f32

__device__ __forceinline__ void gld16(const void* g, void* l) {
    __builtin_amdgcn_global_load_lds(
        (const __attribute__((address_space(1))) unsigned*)g,
        (__attribute__((address_space(3))) unsigned*)l, 16, 0, 0);
}

// ---------------------------------------------------------------------------
__global__ void detect_mask(const unsigned* __restrict__ m, int* __restrict__ flag) {
    __shared__ int bad;
    if (threadIdx.x == 0) bad = 0;
    __syncthreads();
    int ok = 1;
    for (int i = threadIdx.x; i < 4096; i += blockDim.x) {
        unsigned w = m[i];
        if (w > 1u && w != 0x3F800000u) ok = 0;
    }
    if (!ok) atomicOr(&bad, 1);
    __syncthreads();
    if (threadIdx.x == 0) *flag = bad;
}

// ---------------------------------------------------------------------------
// K -> bf16 tiles [h][chunk][8192B], pre-swizzled for linear gld_lds:
// LDS byte o holds K[row=o>>7][colbyte = (o&127) ^ ((row&7)<<4)].
// ---------------------------------------------------------------------------
__global__ __launch_bounds__(256)
void conv_k(const float* __restrict__ K, char* __restrict__ out) {
    const unsigned u = blockIdx.x * 256 + threadIdx.x;   // 16B unit (524288)
    const unsigned w = u & 511;
    const unsigned row = w >> 3;
    const unsigned dcol = (((w & 7) * 16) ^ ((row & 7) << 4)) >> 1;
    const unsigned tile = u >> 9, h = tile >> 6, c = tile & 63;
    const float* src = K + (((size_t)h * KV_) + c * 64 + row) * D_ + dcol;
    f32x4 f0 = *(const f32x4*)src;
    f32x4 f1 = *(const f32x4*)(src + 4);
    bf16x8 b;
    #pragma unroll
    for (int e = 0; e < 4; ++e) { b[e] = (__bf16)f0[e]; b[4 + e] = (__bf16)f1[e]; }
    *(bf16x8*)(out + (size_t)u * 16) = b;
}

// V^T tiles via per-block LDS transpose (row = d, cols = kv), same swizzle.
__global__ __launch_bounds__(256)
void conv_v(const float* __restrict__ V, char* __restrict__ out) {
    __shared__ __bf16 T[64][72];
    const int tile = blockIdx.x;                 // h*64 + c
    const int h = tile >> 6, c = tile & 63;
    const float* src = V + ((size_t)h * KV_ + c * 64) * D_;
    const int tid = threadIdx.x;
    #pragma unroll
    for (int r = 0; r < 4; ++r) {
        const int off = r * 1024 + tid * 4;
        const int kv = off >> 6, d = off & 63;
        f32x4 f = *(const f32x4*)(src + off);
        #pragma unroll
        for (int e = 0; e < 4; ++e) T[d + e][kv] = (__bf16)f[e];
    }
    __syncthreads();
    char* dst = out + (size_t)tile * 8192;
    #pragma unroll
    for (int r = 0; r < 2; ++r) {
        const int u = r * 256 + tid;
        const int d = u >> 3;
        const int kv0 = ((((u & 7) * 16) ^ ((d & 7) << 4))) >> 1;
        *(bf16x8*)(dst + (size_t)u * 16) = *(const bf16x8*)&T[d][kv0];
    }
}

// ---------------------------------------------------------------------------
// attn: 8 waves x 16q = 128 q/block (512 thr); chunk = 64 kv; NSPLIT=2.
// Double-buffered K/V via gld_lds; per-wave swizzled P tile; fused ballot.
// ---------------------------------------------------------------------------
__global__ __launch_bounds__(512, 4)
void attn_fwd(const float* __restrict__ Q,
              const unsigned char* __restrict__ Mb,
              const int* __restrict__ flagp,
              const char* __restrict__ Ktiles,
              const char* __restrict__ Vtiles,
              float* __restrict__ Part,
              float* __restrict__ Ls)
{
    __shared__ char smem[49152];          // 2 x (K 8KB | V 8KB) + 8 x 2KB P

    const int tid  = threadIdx.x;         // 0..511
    const int wave = tid >> 6, lane = tid & 63;
    const int lq   = lane & 15, g = lane >> 4;
    const int swz  = (lq & 7) << 4;

    // XCD swizzle (512 % 8 == 0): 64 consecutive wg per XCD = 2 heads
    const int b  = blockIdx.x;
    const int wg = (b & 7) * 64 + (b >> 3);
    const int h  = wg >> 5;
    const int qt = (wg >> 1) & 15, split = wg & 1;
    const int q0w = qt * 128 + wave * 16;
    const int q_g = q0w + lq;

    const bool byteMode = (*flagp != 0);
    const unsigned* Mw = (const unsigned*)Mb;

    // Q fragments (B operand): lane holds Q[q_g][g*8 + 32*kk + e]
    bf16x8 bq[2];
    {
        const float* qrow = Q + ((size_t)h * S_ + q_g) * D_ + g * 8;
        #pragma unroll
        for (int kk = 0; kk < 2; ++kk) {
            f32x4 f0 = *(const f32x4*)(qrow + 32 * kk);
            f32x4 f1 = *(const f32x4*)(qrow + 32 * kk + 4);
            bf16x8 bb;
            #pragma unroll
            for (int e = 0; e < 4; ++e) { bb[e] = (__bf16)f0[e]; bb[4 + e] = (__bf16)f1[e]; }
            bq[kk] = bb;
        }
    }

    const char* gK = Ktiles + (size_t)h * 64 * 8192;
    const char* gV = Vtiles + (size_t)h * 64 * 8192;
    char* Pb = smem + 32768 + wave * 2048;

    float lsum = 0.f;
    f32x4 acc[4] = {};

    auto stage = [&](int buf, int c) {    // 512 thr x 16B = 8KB per gld pass
        const char* sk = gK + (size_t)c * 8192 + tid * 16;
        const char* sv = gV + (size_t)c * 8192 + tid * 16;
        char* dk = smem + buf * 16384 + tid * 16;
        gld16(sk, dk);
        gld16(sv, dk + 8192);
    };

    // --- fused mask streaming: wave covers its 16 q rows x 64 kv per chunk
    unsigned mreg[16];
    auto load_bits = [&](int cc) {
        if (byteMode) {
            const unsigned char* base = Mb + ((size_t)h * S_ + q0w) * KV_ + (size_t)cc * 64 + lane;
            #pragma unroll
            for (int i = 0; i < 16; ++i) mreg[i] = base[(size_t)i * KV_];
        } else {
            const unsigned* base = Mw + ((size_t)h * S_ + q0w) * KV_ + (size_t)cc * 64 + lane;
            #pragma unroll
            for (int i = 0; i < 16; ++i) mreg[i] = base[(size_t)i * KV_];
        }
    };
    auto ballot_bits = [&]() -> unsigned long long {
        unsigned long long sav = 0;
        #pragma unroll
        for (int i = 0; i < 16; ++i) {
            unsigned long long bal = __ballot(mreg[i] != 0u);
            if (lq == i) sav = bal;       // all 4 g-lanes of row i keep its word
        }
        return sav;
    };

    const int cs = split * CPB, ce = cs + CPB;
    load_bits(cs);
    stage(0, cs);
    unsigned long long mb_cur = ballot_bits();
    __syncthreads();
    int cur = 0;

    for (int c = cs; c < ce; ++c) {
        const bool more = (c + 1 < ce);
        if (more) load_bits(c + 1);
        if (more) stage(cur ^ 1, c + 1);
        const unsigned long long mb = mb_cur;
        const char* Kb = smem + cur * 16384;
        const char* Vb = Kb + 8192;

        // ---- QK^T (swapped): lane holds s for q=q_g, kv = 16t + 4g + i
        f32x4 st[4] = {};
        __builtin_amdgcn_s_setprio(1);
        #pragma unroll
        for (int t = 0; t < 4; ++t) {
            #pragma unroll
            for (int kk = 0; kk < 2; ++kk) {
                bf16x8 ak = *(const bf16x8*)(Kb + (16 * t + lq) * 128 + ((16 * g + 64 * kk) ^ swz));
                st[t] = __builtin_amdgcn_mfma_f32_16x16x32_bf16(ak, bq[kk], st[t], 0, 0, 0);
            }
        }
        __builtin_amdgcn_s_setprio(0);

        // ---- p = exp2(fma(s)); lsum; dropout; P -> per-wave swizzled LDS
        #pragma unroll
        for (int t = 0; t < 4; ++t) {
            bf16x4 pb;
            #pragma unroll
            for (int i = 0; i < 4; ++i) {
                const int kvl = 16 * t + 4 * g + i;
                const int kvg = c * 64 + kvl;
                const bool one = (kvg < S_) ? (kvg > q_g) : (kvg - S_ <= q_g);
                float v = fmaf(st[t][i], C_SC, one ? C_ONE : C_ZRO);
                float pp = exp2f(v);
                lsum += pp;
                pb[i] = (__bf16)(((mb >> kvl) & 1) ? pp : 0.f);
            }
            *(bf16x4*)(Pb + lq * 128 + ((32 * t + 8 * g) ^ swz)) = pb;
        }

        asm volatile("s_waitcnt lgkmcnt(0)" ::: "memory");
        __builtin_amdgcn_sched_barrier(0);

        // ---- PV: acc += P[16q x 64kv] @ V[64kv x 64d]
        __builtin_amdgcn_s_setprio(1);
        #pragma unroll
        for (int c2 = 0; c2 < 2; ++c2) {
            bf16x8 ap = *(const bf16x8*)(Pb + lq * 128 + ((64 * c2 + 16 * g) ^ swz));
            #pragma unroll
            for (int nt = 0; nt < 4; ++nt) {
                bf16x8 bv = *(const bf16x8*)(Vb + (16 * nt + lq) * 128 + ((64 * c2 + 16 * g) ^ swz));
                acc[nt] = __builtin_amdgcn_mfma_f32_16x16x32_bf16(ap, bv, acc[nt], 0, 0, 0);
            }
        }
        __builtin_amdgcn_s_setprio(0);

        // ---- ballot chunk c+1 (mask loads drained by compiler-counted vmcnt)
        if (more) mb_cur = ballot_bits();

        __syncthreads();     // readers done + next stage drained
        cur ^= 1;
    }

    // ---- epilogue
    lsum += __shfl_xor(lsum, 16);
    lsum += __shfl_xor(lsum, 32);
    if (g == 0) Ls[((size_t)split * H_ + h) * S_ + q_g] = lsum;

    float* pa = Part + (((size_t)split * H_ + h) * S_ + q0w + 4 * g) * D_;
    #pragma unroll
    for (int i = 0; i < 4; ++i)
        #pragma unroll
        for (int nt = 0; nt < 4; ++nt)
            pa[i * D_ + nt * 16 + lq] = acc[nt][i];
}

// out = KEEP * (part0 + part1) / (l0 + l1)
__global__ __launch_bounds__(256)
void combine(const float* __restrict__ Part, const float* __restrict__ Ls,
             float* __restrict__ Out) {
    const int idx = blockIdx.x * 256 + threadIdx.x;   // H*S*16
    const int r  = idx >> 4;
    const int dg = (idx & 15) * 4;
    const f32x4 a = *(const f32x4*)(Part + (size_t)r * D_ + dg);
    const f32x4 b = *(const f32x4*)(Part + (size_t)(H_ * S_ + r) * D_ + dg);
    const float l = Ls[r] + Ls[H_ * S_ + r];
    const float s = KEEP_SCALE / l;
    f32x4 o;
    #pragma unroll
    for (int e = 0; e < 4; ++e) o[e] = (a[e] + b[e]) * s;
    *(f32x4*)(Out + (size_t)r * D_ + dg) = o;
}

extern "C" void kernel_launch(void* const* d_in, const int* in_sizes, int n_in,
                              void* d_out, int out_size, void* d_ws, size_t ws_size,
                              hipStream_t stream) {
    const float* Q = (const float*)d_in[0];
    const float* K = (const float*)d_in[1];
    const float* V = (const float*)d_in[2];
    const unsigned char* M = (const unsigned char*)d_in[3];
    char* ws = (char*)d_ws;
    int* flag = (int*)(ws + WS_FLAG);
    char* kt = ws + WS_K;
    char* vt = ws + WS_V;
    float* part = (float*)(ws + WS_PART);
    float* ls = (float*)(ws + WS_LS);

    detect_mask<<<1, 256, 0, stream>>>((const unsigned*)M, flag);
    conv_k<<<2048, 256, 0, stream>>>(K, kt);
    conv_v<<<1024, 256, 0, stream>>>(V, vt);
    attn_fwd<<<512, 512, 0, stream>>>(Q, M, flag, kt, vt, part, ls);
    combine<<<2048, 256, 0, stream>>>(part, ls, (float*)d_out);
}